// Round 11
// baseline (57.090 us; speedup 1.0000x reference)
//
#include <hip/hip_runtime.h>

#define BB 16
#define CC 64
#define DD 16
#define HW 2304     // 48*48
#define HID 16
#define NEG_SLOPE 0.01f
#define CH4 9216    // float4 stride between channels at fixed (b,d)

using f4 = __attribute__((ext_vector_type(4))) float;

__device__ __forceinline__ uint2 pack_bf16x4(f4 v) {
    uint2 r;
    asm("v_cvt_pk_bf16_f32 %0, %1, %2" : "=v"(r.x) : "v"(v.x), "v"(v.y));
    asm("v_cvt_pk_bf16_f32 %0, %1, %2" : "=v"(r.y) : "v"(v.z), "v"(v.w));
    return r;
}

__device__ __forceinline__ f4 unpack_mul(uint2 p, float g) {
    f4 v;
    v.x = __uint_as_float(p.x << 16) * g;
    v.y = __uint_as_float(p.x & 0xffff0000u) * g;
    v.z = __uint_as_float(p.y << 16) * g;
    v.w = __uint_as_float(p.y & 0xffff0000u) * g;
    return v;
}

__device__ __forceinline__ f4 gmul(f4 v, float g) {
    v.x *= g; v.y *= g; v.z *= g; v.w *= g;
    return v;
}

// One block per (b,d) slice, gate block-local (R8/R10 proved any cross-block
// coupling is poison). Per wave (4 channels x 9 f4):
//   ch0,ch1 -> registers (18 uint2, R8-proven spill-free)
//   ch2     -> LDS (9 slots, 73.7 KB)
//   ch3     -> pool-only in phase 1; RE-READ in phase 3 interleaved with the
//              NT-store stream (3 loads hidden under every 9 stores), turning
//              the strictly-serial read->write structure into partial overlap.
__global__ __launch_bounds__(1024) void fused_se_kernel(
    const float* __restrict__ x,
    const float* __restrict__ w1, const float* __restrict__ b1,
    const float* __restrict__ w2, const float* __restrict__ b2,
    float* __restrict__ out)
{
    const int bd   = blockIdx.x;
    const int b    = bd >> 4;
    const int d    = bd & 15;
    const int tid  = threadIdx.x;
    const int wave = tid >> 6;
    const int lane = tid & 63;

    __shared__ uint2 stage[9][1024];       // 73,728 B (ch2 per wave)
    __shared__ float pooled[CC];
    __shared__ float hbuf[HID];
    __shared__ float gate_s[CC];

    const size_t base4 = ((size_t)(b * CC) * DD + d) * (HW / 4);
    const f4* xb = (const f4*)x + base4 + lane;

    uint2 rv[18];
    float csum[4];

    // ---- Phase 1: read + pool; retain ch0,ch1 (regs) and ch2 (LDS) ----
    #pragma unroll
    for (int i = 0; i < 4; ++i) {
        const f4* p = xb + (size_t)(wave * 4 + i) * CH4;
        float s = 0.f;
        #pragma unroll
        for (int j = 0; j < 9; ++j) {
            f4 v = p[j * 64];
            s += (v.x + v.y) + (v.z + v.w);
            if (i < 2)       rv[i * 9 + j] = pack_bf16x4(v);
            else if (i == 2) stage[j][tid] = pack_bf16x4(v);
            // i == 3: pool only, re-read in phase 3 (MALL-warm)
        }
        csum[i] = s;
    }
    // Batched reduces: 4 interleaved shuffle chains (4-way ILP) instead of
    // 4 serial chains blocking the load-issue path.
    #pragma unroll
    for (int m = 32; m; m >>= 1) {
        #pragma unroll
        for (int i = 0; i < 4; ++i) csum[i] += __shfl_xor(csum[i], m, 64);
    }
    if (lane == 0) {
        #pragma unroll
        for (int i = 0; i < 4; ++i) pooled[wave * 4 + i] = csum[i] * (1.0f / HW);
    }
    __syncthreads();

    // ---- Phase 2: tiny MLP (wave-parallel layer 1) ----
    {
        float v = w1[wave * CC + lane] * pooled[lane];
        #pragma unroll
        for (int m = 32; m; m >>= 1) v += __shfl_xor(v, m, 64);
        if (lane == 0) {
            float acc = v + b1[wave];
            hbuf[wave] = acc >= 0.f ? acc : NEG_SLOPE * acc;
        }
    }
    __syncthreads();
    if (tid < CC) {
        float acc = b2[tid];
        #pragma unroll
        for (int o = 0; o < HID; ++o) acc += w2[tid * HID + o] * hbuf[o];
        gate_s[tid] = 1.0f / (1.0f + expf(-acc));
    }
    __syncthreads();

    // ---- Phase 3: writes overlapped with ch3 re-read ----
    const float g0 = gate_s[wave * 4 + 0];
    const float g1 = gate_s[wave * 4 + 1];
    const float g2 = gate_s[wave * 4 + 2];
    const float g3 = gate_s[wave * 4 + 3];
    f4* ob = (f4*)out + base4 + lane;
    const f4* p3 = xb + (size_t)(wave * 4 + 3) * CH4;
    f4* q0 = ob + (size_t)(wave * 4 + 0) * CH4;
    f4* q1 = ob + (size_t)(wave * 4 + 1) * CH4;
    f4* q2 = ob + (size_t)(wave * 4 + 2) * CH4;
    f4* q3 = ob + (size_t)(wave * 4 + 3) * CH4;

    #pragma unroll
    for (int kb = 0; kb < 3; ++kb) {
        // issue 3 ch3 re-reads; latency hides under the 9 stores below
        f4 ra = p3[(3 * kb + 0) * 64];
        f4 rb = p3[(3 * kb + 1) * 64];
        f4 rc = p3[(3 * kb + 2) * 64];
        #pragma unroll
        for (int j = 3 * kb; j < 3 * kb + 3; ++j) {
            __builtin_nontemporal_store(unpack_mul(rv[j],      g0), q0 + j * 64);
            __builtin_nontemporal_store(unpack_mul(rv[9 + j],  g1), q1 + j * 64);
            __builtin_nontemporal_store(unpack_mul(stage[j][tid], g2), q2 + j * 64);
        }
        __builtin_nontemporal_store(gmul(ra, g3), q3 + (3 * kb + 0) * 64);
        __builtin_nontemporal_store(gmul(rb, g3), q3 + (3 * kb + 1) * 64);
        __builtin_nontemporal_store(gmul(rc, g3), q3 + (3 * kb + 2) * 64);
    }
}

extern "C" void kernel_launch(void* const* d_in, const int* in_sizes, int n_in,
                              void* d_out, int out_size, void* d_ws, size_t ws_size,
                              hipStream_t stream) {
    const float* x  = (const float*)d_in[0];
    const float* w1 = (const float*)d_in[1];
    const float* b1 = (const float*)d_in[2];
    const float* w2 = (const float*)d_in[3];
    const float* b2 = (const float*)d_in[4];
    float* out = (float*)d_out;

    fused_se_kernel<<<BB * DD, 1024, 0, stream>>>(x, w1, b1, w2, b2, out);
}

// Round 12
// 54.915 us; speedup vs baseline: 1.0396x; 1.0396x over previous
//
#include <hip/hip_runtime.h>

#define BB 16
#define CC 64
#define DD 16
#define HW 2304     // 48*48
#define HID 16
#define NEG_SLOPE 0.01f
#define CH4 9216    // float4 stride between channels at fixed (b,d)

using f4 = __attribute__((ext_vector_type(4))) float;

__device__ __forceinline__ uint2 pack_bf16x4(f4 v) {
    uint2 r;
    asm("v_cvt_pk_bf16_f32 %0, %1, %2" : "=v"(r.x) : "v"(v.x), "v"(v.y));
    asm("v_cvt_pk_bf16_f32 %0, %1, %2" : "=v"(r.y) : "v"(v.z), "v"(v.w));
    return r;
}

__device__ __forceinline__ f4 unpack_mul(uint2 p, float g) {
    f4 v;
    v.x = __uint_as_float(p.x << 16) * g;
    v.y = __uint_as_float(p.x & 0xffff0000u) * g;
    v.z = __uint_as_float(p.y << 16) * g;
    v.w = __uint_as_float(p.y & 0xffff0000u) * g;
    return v;
}

// R7 structure (best: 53.5 us) + DETERMINISTIC LLC policy:
//   channels i in {0,2}: regular loads -> stable Infinity-Cache resident set
//   channels i in {1,3}: non-temporal loads -> never allocate, always HBM
// Every block then has exactly 50% LLC hits instead of LRU-random luck;
// kernel time was set by all-miss straggler blocks (E[max], not E[mean]).
// nt channels issued FIRST so HBM latency hides under LLC-hit processing.
// Whole slice retained on-chip as bf16: 17 reg slots + 19 LDS slots. Gate is
// block-local (R8/R10: cross-block coupling is poison). NT stores (builtin).
__global__ __launch_bounds__(1024) void fused_se_kernel(
    const float* __restrict__ x,
    const float* __restrict__ w1, const float* __restrict__ b1,
    const float* __restrict__ w2, const float* __restrict__ b2,
    float* __restrict__ out)
{
    const int bd   = blockIdx.x;
    const int b    = bd >> 4;
    const int d    = bd & 15;
    const int tid  = threadIdx.x;
    const int wave = tid >> 6;
    const int lane = tid & 63;

    __shared__ uint2 stage[19][1024];      // 155,648 B
    __shared__ float pooled[CC];
    __shared__ float hbuf[HID];
    __shared__ float gate_s[CC];

    const size_t base4 = ((size_t)(b * CC) * DD + d) * (HW / 4);
    const f4* xb = (const f4*)x + base4 + lane;

    // per-channel storage map: ch0 -> 5 reg + 4 LDS, ch1..3 -> 4 reg + 5 LDS
    uint2 rv[17];
    float csum[4];

    // ---- Phase 1: read + pool + pack on-chip; nt channels (1,3) first ----
    constexpr int ORDER[4] = {1, 3, 0, 2};
    #pragma unroll
    for (int k = 0; k < 4; ++k) {
        const int i = ORDER[k];
        const bool is_nt = (i & 1);
        const f4* p = xb + (size_t)(wave * 4 + i) * CH4;
        const int nreg  = (i == 0) ? 5 : 4;
        const int rbase = (i == 0) ? 0 : 5 + (i - 1) * 4;
        const int lbase = (i == 0) ? 0 : 4 + (i - 1) * 5;
        float s = 0.f;
        #pragma unroll
        for (int j = 0; j < 9; ++j) {
            f4 v = is_nt ? __builtin_nontemporal_load(p + j * 64) : p[j * 64];
            s += (v.x + v.y) + (v.z + v.w);
            uint2 pk = pack_bf16x4(v);
            if (j < nreg) rv[rbase + j] = pk;
            else          stage[lbase + (j - nreg)][tid] = pk;
        }
        csum[i] = s;
    }
    // batched shuffle reduces (4-way ILP)
    #pragma unroll
    for (int m = 32; m; m >>= 1) {
        #pragma unroll
        for (int i = 0; i < 4; ++i) csum[i] += __shfl_xor(csum[i], m, 64);
    }
    if (lane == 0) {
        #pragma unroll
        for (int i = 0; i < 4; ++i) pooled[wave * 4 + i] = csum[i] * (1.0f / HW);
    }
    __syncthreads();

    // ---- Phase 2: tiny MLP (wave-parallel layer 1) ----
    {
        float v = w1[wave * CC + lane] * pooled[lane];
        #pragma unroll
        for (int m = 32; m; m >>= 1) v += __shfl_xor(v, m, 64);
        if (lane == 0) {
            float acc = v + b1[wave];
            hbuf[wave] = acc >= 0.f ? acc : NEG_SLOPE * acc;
        }
    }
    __syncthreads();
    if (tid < CC) {
        float acc = b2[tid];
        #pragma unroll
        for (int o = 0; o < HID; ++o) acc += w2[tid * HID + o] * hbuf[o];
        gate_s[tid] = 1.0f / (1.0f + expf(-acc));
    }
    __syncthreads();

    // ---- Phase 3: unpack, multiply, NT store ----
    f4* ob = (f4*)out + base4 + lane;
    #pragma unroll
    for (int i = 0; i < 4; ++i) {
        const float gv = gate_s[wave * 4 + i];
        f4* q = ob + (size_t)(wave * 4 + i) * CH4;
        const int nreg  = (i == 0) ? 5 : 4;
        const int rbase = (i == 0) ? 0 : 5 + (i - 1) * 4;
        const int lbase = (i == 0) ? 0 : 4 + (i - 1) * 5;
        #pragma unroll
        for (int j = 0; j < 9; ++j) {
            uint2 pk = (j < nreg) ? rv[rbase + j] : stage[lbase + (j - nreg)][tid];
            __builtin_nontemporal_store(unpack_mul(pk, gv), q + j * 64);
        }
    }
}

extern "C" void kernel_launch(void* const* d_in, const int* in_sizes, int n_in,
                              void* d_out, int out_size, void* d_ws, size_t ws_size,
                              hipStream_t stream) {
    const float* x  = (const float*)d_in[0];
    const float* w1 = (const float*)d_in[1];
    const float* b1 = (const float*)d_in[2];
    const float* w2 = (const float*)d_in[3];
    const float* b2 = (const float*)d_in[4];
    float* out = (float*)d_out;

    fused_se_kernel<<<BB * DD, 1024, 0, stream>>>(x, w1, b1, w2, b2, out);
}

// Round 13
// 54.725 us; speedup vs baseline: 1.0432x; 1.0035x over previous
//
#include <hip/hip_runtime.h>

#define BB 16
#define CC 64
#define DD 16
#define HW 2304     // 48*48
#define HID 16
#define NEG_SLOPE 0.01f
#define CH4 9216    // float4 stride between channels at fixed (b,d)

using f4 = __attribute__((ext_vector_type(4))) float;

__device__ __forceinline__ uint2 pack_bf16x4(f4 v) {
    uint2 r;
    asm("v_cvt_pk_bf16_f32 %0, %1, %2" : "=v"(r.x) : "v"(v.x), "v"(v.y));
    asm("v_cvt_pk_bf16_f32 %0, %1, %2" : "=v"(r.y) : "v"(v.z), "v"(v.w));
    return r;
}

__device__ __forceinline__ f4 unpack_mul(uint2 p, float g) {
    f4 v;
    v.x = __uint_as_float(p.x << 16) * g;
    v.y = __uint_as_float(p.x & 0xffff0000u) * g;
    v.z = __uint_as_float(p.y << 16) * g;
    v.w = __uint_as_float(p.y & 0xffff0000u) * g;
    return v;
}

__device__ __forceinline__ void load_ch(const f4* __restrict__ p, f4 t[9]) {
    #pragma unroll
    for (int j = 0; j < 9; ++j) t[j] = p[j * 64];
}

// Pack one channel's 9 f4 into the retention map (compile-time channel index).
// ch0 -> 5 reg + 4 LDS slots; ch1..3 -> 4 reg + 5 LDS slots.
template<int I>
__device__ __forceinline__ void pack_ch(const f4 t[9], uint2 rv[17],
                                        uint2 (*stage)[1024], int tid,
                                        float& csum) {
    constexpr int nreg  = (I == 0) ? 5 : 4;
    constexpr int rbase = (I == 0) ? 0 : 5 + (I - 1) * 4;
    constexpr int lbase = (I == 0) ? 0 : 4 + (I - 1) * 5;
    float s = 0.f;
    #pragma unroll
    for (int j = 0; j < 9; ++j) {
        s += (t[j].x + t[j].y) + (t[j].z + t[j].w);
        uint2 pk = pack_bf16x4(t[j]);
        if (j < nreg) rv[rbase + j] = pk;
        else          stage[lbase + (j - nreg)][tid] = pk;
    }
    csum = s;
}

// R7 structure (proven best) + two changes:
//  1. amdgpu_waves_per_eu(4,4): pins 4 waves/EU (= our 16 waves/CU, 1 block),
//     raising the VGPR cap from the compiler's 2-block-targeted 64 to 128 —
//     R7's phase-1 load pipeline was throttled by ~34 permanently-live packed
//     VGPRs inside a 64-VGPR budget.
//  2. Explicit double-buffered phase 1: one channel's 9 loads always in
//     flight while the previous channel packs (72 VGPR temps + 34 retained).
__global__ __launch_bounds__(1024)
__attribute__((amdgpu_waves_per_eu(4, 4)))
void fused_se_kernel(
    const float* __restrict__ x,
    const float* __restrict__ w1, const float* __restrict__ b1,
    const float* __restrict__ w2, const float* __restrict__ b2,
    float* __restrict__ out)
{
    const int bd   = blockIdx.x;
    const int b    = bd >> 4;
    const int d    = bd & 15;
    const int tid  = threadIdx.x;
    const int wave = tid >> 6;
    const int lane = tid & 63;

    __shared__ uint2 stage[19][1024];      // 155,648 B
    __shared__ float pooled[CC];
    __shared__ float hbuf[HID];
    __shared__ float gate_s[CC];

    const size_t base4 = ((size_t)(b * CC) * DD + d) * (HW / 4);
    const f4* xb = (const f4*)x + base4 + lane;

    uint2 rv[17];
    float csum[4];

    // ---- Phase 1: software-pipelined read + pool + pack ----
    f4 ta[9], tb[9];
    load_ch(xb + (size_t)(wave * 4 + 0) * CH4, ta);
    load_ch(xb + (size_t)(wave * 4 + 1) * CH4, tb);
    pack_ch<0>(ta, rv, stage, tid, csum[0]);
    load_ch(xb + (size_t)(wave * 4 + 2) * CH4, ta);
    pack_ch<1>(tb, rv, stage, tid, csum[1]);
    load_ch(xb + (size_t)(wave * 4 + 3) * CH4, tb);
    pack_ch<2>(ta, rv, stage, tid, csum[2]);
    pack_ch<3>(tb, rv, stage, tid, csum[3]);

    // batched shuffle reduces (4-way ILP)
    #pragma unroll
    for (int m = 32; m; m >>= 1) {
        #pragma unroll
        for (int i = 0; i < 4; ++i) csum[i] += __shfl_xor(csum[i], m, 64);
    }
    if (lane == 0) {
        #pragma unroll
        for (int i = 0; i < 4; ++i) pooled[wave * 4 + i] = csum[i] * (1.0f / HW);
    }
    __syncthreads();

    // ---- Phase 2: tiny MLP (wave-parallel layer 1) ----
    {
        float v = w1[wave * CC + lane] * pooled[lane];
        #pragma unroll
        for (int m = 32; m; m >>= 1) v += __shfl_xor(v, m, 64);
        if (lane == 0) {
            float acc = v + b1[wave];
            hbuf[wave] = acc >= 0.f ? acc : NEG_SLOPE * acc;
        }
    }
    __syncthreads();
    if (tid < CC) {
        float acc = b2[tid];
        #pragma unroll
        for (int o = 0; o < HID; ++o) acc += w2[tid * HID + o] * hbuf[o];
        gate_s[tid] = 1.0f / (1.0f + expf(-acc));
    }
    __syncthreads();

    // ---- Phase 3: unpack, multiply, NT store ----
    f4* ob = (f4*)out + base4 + lane;
    #pragma unroll
    for (int i = 0; i < 4; ++i) {
        const float gv = gate_s[wave * 4 + i];
        f4* q = ob + (size_t)(wave * 4 + i) * CH4;
        const int nreg  = (i == 0) ? 5 : 4;
        const int rbase = (i == 0) ? 0 : 5 + (i - 1) * 4;
        const int lbase = (i == 0) ? 0 : 4 + (i - 1) * 5;
        #pragma unroll
        for (int j = 0; j < 9; ++j) {
            uint2 pk = (j < nreg) ? rv[rbase + j] : stage[lbase + (j - nreg)][tid];
            __builtin_nontemporal_store(unpack_mul(pk, gv), q + j * 64);
        }
    }
}

extern "C" void kernel_launch(void* const* d_in, const int* in_sizes, int n_in,
                              void* d_out, int out_size, void* d_ws, size_t ws_size,
                              hipStream_t stream) {
    const float* x  = (const float*)d_in[0];
    const float* w1 = (const float*)d_in[1];
    const float* b1 = (const float*)d_in[2];
    const float* w2 = (const float*)d_in[3];
    const float* b2 = (const float*)d_in[4];
    float* out = (float*)d_out;

    fused_se_kernel<<<BB * DD, 1024, 0, stream>>>(x, w1, b1, w2, b2, out);
}